// Round 4
// baseline (6746.198 us; speedup 1.0000x reference)
//
#include <hip/hip_runtime.h>
#include <cmath>

#define LOG2E 1.44269504088896340736f
#define TMAX 2048

#if __has_builtin(__builtin_amdgcn_exp2f)
#define EXP2F(x) __builtin_amdgcn_exp2f(x)
#else
#define EXP2F(x) exp2f(x)
#endif
#if __has_builtin(__builtin_amdgcn_rcpf)
#define RCPF(x) __builtin_amdgcn_rcpf(x)
#else
#define RCPF(x) (1.0f / (x))
#endif

typedef float float2v __attribute__((ext_vector_type(2)));
typedef float float4v __attribute__((ext_vector_type(4)));

__device__ __forceinline__ float fexp(float x)  { return EXP2F(x * LOG2E); }
// tanh(x) = 1 - 2/(1 + e^{2x})
__device__ __forceinline__ float ftanh(float x) { return 1.0f - 2.0f * RCPF(1.0f + EXP2F(x * (2.0f * LOG2E))); }
// _step(x) = (tanh(5x)+1)/2 = sigmoid(10x)
__device__ __forceinline__ float fstep(float x) { return RCPF(1.0f + EXP2F(x * (-10.0f * LOG2E))); }
__device__ __forceinline__ float fsinh(float x) { float e = fexp(x); return 0.5f * (e - RCPF(e)); }

__device__ __forceinline__ int fadd_i(int a, int b) {
    return __builtin_bit_cast(int, __builtin_bit_cast(float, a) + __builtin_bit_cast(float, b));
}

// full-wave (64 lane) sum via DPP tree; TOTAL VALID IN LANE 63 ONLY (no
// broadcast readlane -- callers that need a uniform value readlane(63) once).
__device__ __forceinline__ float wave_sum63(float x) {
    int v = __builtin_bit_cast(int, x);
    v = fadd_i(v, __builtin_amdgcn_update_dpp(0, v, 0x111, 0xF, 0xF, true)); // row_shr:1
    v = fadd_i(v, __builtin_amdgcn_update_dpp(0, v, 0x112, 0xF, 0xF, true)); // row_shr:2
    v = fadd_i(v, __builtin_amdgcn_update_dpp(0, v, 0x114, 0xF, 0xF, true)); // row_shr:4
    v = fadd_i(v, __builtin_amdgcn_update_dpp(0, v, 0x118, 0xF, 0xF, true)); // row_shr:8
    v = fadd_i(v, __builtin_amdgcn_update_dpp(0, v, 0x142, 0xA, 0xF, true)); // row_bcast:15
    v = fadd_i(v, __builtin_amdgcn_update_dpp(0, v, 0x143, 0xC, 0xF, true)); // row_bcast:31
    return __builtin_bit_cast(float, v);
}

// broadcast lane l's value to all lanes (lands in SGPR)
__device__ __forceinline__ float rl(float x, int l) {
    return __builtin_bit_cast(float, __builtin_amdgcn_readlane(__builtin_bit_cast(int, x), l));
}

// packed fp32 fma: d = a*b + c on both 32-bit halves (one VOP3P inst)
__device__ __forceinline__ float2v pk_fma(float2v a, float2v b, float2v c) {
    float2v d;
    asm("v_pk_fma_f32 %0, %1, %2, %3" : "=v"(d) : "v"(a), "v"(b), "v"(c));
    return d;
}

__global__ __launch_bounds__(64, 1)
void exphydro_kernel(const float* __restrict__ g_snow, const float* __restrict__ g_water,
                     const float* __restrict__ g_pr, const float* __restrict__ g_tm,
                     const float* __restrict__ g_ld, const float* __restrict__ g_t,
                     const float* __restrict__ W1, const float* __restrict__ b1,
                     const float* __restrict__ W2, const float* __restrict__ b2,
                     const float* __restrict__ W3, const float* __restrict__ b3,
                     const float* __restrict__ W4, const float* __restrict__ b4,
                     float* __restrict__ out, int T)
{
    const int lane = threadIdx.x;
    const int b = blockIdx.x;

    // forcing interleaved per timestep: {pr, tm, ld, t} -- one b128 read per point
    __shared__ __align__(16) float4v s_f[TMAX];
    __shared__ __align__(16) float hb2[64];
    __shared__ __align__(16) float hb3[64];

    for (int i = lane; i < T; i += 64) {
        float4v v;
        v.x = g_pr[b * T + i];
        v.y = g_tm[b * T + i];
        v.z = g_ld[b * T + i];
        v.w = g_t[i];
        s_f[i] = v;
    }

    // weights: lane i holds column i of W1/W2/W3 (pair-packed) and row i of W4
    float w1r[4], w4r[5], b4r[5];
    float2v w2p[32], w3p[32];
#pragma unroll
    for (int j = 0; j < 4; ++j) w1r[j] = W1[j * 64 + lane];
    float b1v = b1[lane];
#pragma unroll
    for (int k = 0; k < 32; ++k) {
        w2p[k] = float2v{W2[(2 * k) * 64 + lane], W2[(2 * k + 1) * 64 + lane]};
        w3p[k] = float2v{W3[(2 * k) * 64 + lane], W3[(2 * k + 1) * 64 + lane]};
    }
    float b2v = b2[lane];
    float b3v = b3[lane];
#pragma unroll
    for (int k = 0; k < 5; ++k) { w4r[k] = W4[lane * 5 + k]; b4r[k] = b4[k]; }

    __syncthreads();

    // 64x64 matvec: broadcast x via LDS (single wave: DS pipe in-order, no
    // barrier), packed-fp32 FMAs, 4 independent packed accumulator chains.
    auto matvec64 = [&](float* hbuf, const float2v (&w)[32], float xlane, float bias) -> float {
        hbuf[lane] = xlane;
        float2v a0 = float2v{bias, 0.0f}, a1 = float2v{0.0f, 0.0f},
                a2 = float2v{0.0f, 0.0f}, a3 = float2v{0.0f, 0.0f};
#pragma unroll
        for (int j = 0; j < 64; j += 8) {
            float4v h0 = *reinterpret_cast<const float4v*>(&hbuf[j]);
            float4v h1 = *reinterpret_cast<const float4v*>(&hbuf[j + 4]);
            a0 = pk_fma(w[j / 2 + 0], __builtin_shufflevector(h0, h0, 0, 1), a0);
            a1 = pk_fma(w[j / 2 + 1], __builtin_shufflevector(h0, h0, 2, 3), a1);
            a2 = pk_fma(w[j / 2 + 2], __builtin_shufflevector(h1, h1, 0, 1), a2);
            a3 = pk_fma(w[j / 2 + 3], __builtin_shufflevector(h1, h1, 2, 3), a3);
        }
        float2v s = (a0 + a1) + (a2 + a3);
        return s.x + s.y;
    };

    // MLP: base = b1 + W1[2]*pr + W1[3]*tm precomputed; o[0..4] valid in LANE 63.
    auto mlp_o = [&](float base, float y0v, float y1v, float* o) {
        float h1 = ftanh(fmaf(w1r[0], y0v, fmaf(w1r[1], y1v, base)));
        float h2 = ftanh(matvec64(hb2, w2p, h1, b2v));
        float h3 = ftanh(matvec64(hb3, w3p, h2, b3v));
#pragma unroll
        for (int k = 0; k < 5; ++k) o[k] = wave_sum63(w4r[k] * h3) + b4r[k];
    };

    // rhs: d0,d1 returned wave-uniform (readlane 63); o4 valid in lane 63.
    auto rhs = [&](float base, float y0v, float y1v, float ld, float stepNT,
                   float& d0, float& d1, float& o4) {
        // state-only nonlinearities issued first -> overlap with the matvecs
        float step0 = fstep(y0v);
        float st1   = fstep(y1v);
        float o[5];
        mlp_o(base, y0v, y1v, o);
        float psnow = fmaxf(0.0f, fsinh(o[0]) * stepNT);
        float prain = fmaxf(0.0f, fsinh(o[1]));
        float melt  = fmaxf(0.0f, step0 * fsinh(o[2]));
        float eq    = st1 * fmaf(fexp(o[3]), ld, fexp(o[4]));
        float d0l = psnow - melt;
        float d1l = (prain + melt) - eq;
        d0 = rl(d0l, 63);
        d1 = rl(d1l, 63);
        o4 = o[4];
    };

    float y0v = g_snow[b * T];
    float y1v = g_water[b * T];

    float4v fc = s_f[0];
    float4v fn = s_f[1];

    for (int st = 0; st < T - 1; ++st) {
        // prefetch next step's forcing; consumed only next iteration
        int pf = st + 2; if (pf > T - 1) pf = T - 1;
        float4v fn2 = s_f[pf];

        // all forcing-derived quantities: off the serial k-chain
        float dt = fn.w - fc.w, half = 0.5f * dt, c6 = dt * (1.0f / 6.0f);
        float prH = 0.5f * (fc.x + fn.x);
        float tmH = 0.5f * (fc.y + fn.y);
        float ldH = 0.5f * (fc.z + fn.z);
        float stepA = fstep(-fc.y), stepH = fstep(-tmH), stepC = fstep(-fn.y);
        float baseA = fmaf(w1r[2], fc.x, fmaf(w1r[3], fc.y, b1v));
        float baseH = fmaf(w1r[2], prH,  fmaf(w1r[3], tmH,  b1v));
        float baseC = fmaf(w1r[2], fn.x, fmaf(w1r[3], fn.y, b1v));

        float k1a, k1b, k2a, k2b, k3a, k3b, k4a, k4b, o4a, o4x;
        rhs(baseA, y0v, y1v, fc.z, stepA, k1a, k1b, o4a);
        rhs(baseH, fmaf(half, k1a, y0v), fmaf(half, k1b, y1v), ldH, stepH, k2a, k2b, o4x);
        // q_out[:, st] == o[4] of the k1 MLP eval; store off the k1->k2 transition
        if (lane == 63) out[b * T + st] = o4a;
        rhs(baseH, fmaf(half, k2a, y0v), fmaf(half, k2b, y1v), ldH, stepH, k3a, k3b, o4x);
        rhs(baseC, fmaf(dt, k3a, y0v),   fmaf(dt, k3b, y1v),   fn.z, stepC, k4a, k4b, o4x);

        y0v = fmaf(c6, (k1a + k4a) + 2.0f * (k2a + k3a), y0v);
        y1v = fmaf(c6, (k1b + k4b) + 2.0f * (k2b + k3b), y1v);

        fc = fn; fn = fn2;
    }

    // last readout at t = T-1 (fc == s_f[T-1] after the loop)
    {
        float base = fmaf(w1r[2], fc.x, fmaf(w1r[3], fc.y, b1v));
        float o[5];
        mlp_o(base, y0v, y1v, o);
        if (lane == 63) out[b * T + (T - 1)] = o[4];
    }
}

extern "C" void kernel_launch(void* const* d_in, const int* in_sizes, int n_in,
                              void* d_out, int out_size, void* d_ws, size_t ws_size,
                              hipStream_t stream) {
    const float* g_snow  = (const float*)d_in[0];
    const float* g_water = (const float*)d_in[1];
    const float* g_pr    = (const float*)d_in[2];
    const float* g_tm    = (const float*)d_in[3];
    const float* g_ld    = (const float*)d_in[4];
    const float* g_t     = (const float*)d_in[5];
    const float* W1 = (const float*)d_in[6];
    const float* b1 = (const float*)d_in[7];
    const float* W2 = (const float*)d_in[8];
    const float* b2 = (const float*)d_in[9];
    const float* W3 = (const float*)d_in[10];
    const float* b3 = (const float*)d_in[11];
    const float* W4 = (const float*)d_in[12];
    const float* b4 = (const float*)d_in[13];

    const int T = in_sizes[5];
    const int B = in_sizes[0] / T;

    exphydro_kernel<<<dim3(B), dim3(64), 0, stream>>>(
        g_snow, g_water, g_pr, g_tm, g_ld, g_t,
        W1, b1, W2, b2, W3, b3, W4, b4,
        (float*)d_out, T);
}